// Round 5
// baseline (331.677 us; speedup 1.0000x reference)
//
#include <hip/hip_runtime.h>

// Performer (FAVOR+) attention, MI355X.
// B=4 N=4096 H=16 D=64 DIM=1024 M=256.
// Pipeline:
//  k_wtrans:  W[k][n] f32 -> wt[g][n][k] fp16   (B^T layout for MFMA)
//  k_omconv:  omega f32 -> fp16
//  k_xconv:   x f32 -> xh fp16
//  k_gemm:    Q,K -> qkv (stride 2048, fp16); V -> transposed in-epilogue to
//             vT[bh][d][n] bf16 (k_vtrans fused away).
//             256x256 tile, BK=32, 3-buf LDS ring, counted vmcnt(6), ONE
//             s_barrier per K-tile, setprio, [16][32] subtile + XOR swizzle.
//  k_kv:      pk = exp(k.om^T - |k|^2/2)/16 ; kv += pk^T v ; pksum
//  k_kvt:     kvt[bh][j][m] bf16: rows 0..63 = kv^T, row 64 = pksum, 65..79 = 0
//  k_out:     kvt staged in LDS once/block, omega in registers,
//             swapped proj mfma(om, q) -> pq^T b64 LDS writes, PV all-LDS.

typedef _Float16 half8 __attribute__((ext_vector_type(8)));
typedef short short8 __attribute__((ext_vector_type(8)));
typedef float f32x4 __attribute__((ext_vector_type(4)));
typedef unsigned short ushort4v __attribute__((ext_vector_type(4)));
typedef unsigned short ushort_t;
typedef unsigned int uint_t;

#define QKV_LD 2048

__device__ __forceinline__ ushort_t f2bf(float f) {
  uint_t u = __builtin_bit_cast(uint_t, f);
  u += 0x7fffu + ((u >> 16) & 1u);
  return (ushort_t)(u >> 16);
}

__device__ __forceinline__ void gload16(const void* g, void* l) {
  __builtin_amdgcn_global_load_lds(
      (const __attribute__((address_space(1))) void*)g,
      (__attribute__((address_space(3))) void*)l, 16, 0, 0);
}

// ---------------- W transpose+convert: wt[g][n][k] = (f16)W_g[k][n] ----------------
__global__ void k_wtrans(const float* __restrict__ Wq, const float* __restrict__ Wk,
                         const float* __restrict__ Wv, _Float16* __restrict__ wt) {
  __shared__ float t[32][33];
  const int g = blockIdx.z;
  const float* W = (g == 0) ? Wq : ((g == 1) ? Wk : Wv);
  const int n0 = blockIdx.x * 32, k0 = blockIdx.y * 32;
  const int tx = threadIdx.x, ty = threadIdx.y;
#pragma unroll
  for (int j = 0; j < 4; ++j)
    t[ty + j * 8][tx] = W[(size_t)(k0 + ty + j * 8) * 1024 + n0 + tx];
  __syncthreads();
  _Float16* o = wt + (size_t)g * 1024 * 1024;
#pragma unroll
  for (int j = 0; j < 4; ++j)
    o[(size_t)(n0 + ty + j * 8) * 1024 + k0 + tx] = (_Float16)t[tx][ty + j * 8];
}

__global__ void k_omconv(const float* __restrict__ omega, _Float16* __restrict__ om) {
  int i = blockIdx.x * 256 + threadIdx.x;
  if (i < 16384) om[i] = (_Float16)omega[i];
}

// ---------------- x convert: xh[n][k] = (f16)x[n][k] ----------------
__global__ __launch_bounds__(256) void k_xconv(const float* __restrict__ x,
                                               _Float16* __restrict__ xh) {
  size_t base = ((size_t)blockIdx.x * 256 + threadIdx.x) * 8;
  float4 f0 = *(const float4*)(x + base);
  float4 f1 = *(const float4*)(x + base + 4);
  half8 h;
  h[0] = (_Float16)f0.x; h[1] = (_Float16)f0.y; h[2] = (_Float16)f0.z; h[3] = (_Float16)f0.w;
  h[4] = (_Float16)f1.x; h[5] = (_Float16)f1.y; h[6] = (_Float16)f1.z; h[7] = (_Float16)f1.w;
  *(half8*)(xh + base) = h;
}

// ---------------- QKV GEMM: 256x256 tile, BK=32, 3-buf ring, 1 barrier/K-tile ----------------
__global__ __launch_bounds__(512, 2) void k_gemm(const _Float16* __restrict__ xh,
                                                 const _Float16* __restrict__ wt,
                                                 ushort_t* __restrict__ qkv,
                                                 ushort_t* __restrict__ vT) {
  __shared__ _Float16 As[3][8192];
  __shared__ _Float16 Bs[3][8192];
  __shared__ ushort_t T[256][72];  // V-transpose staging (epilogue only)
  const int vb = (blockIdx.x & 7) * 96 + (blockIdx.x >> 3);
  const int ct = vb % 12, rt = vb / 12;
  const int col0 = ct * 256, row0 = rt * 256;
  const int g = col0 >> 10;  // 0=Q 1=K 2=V
  const int col0g = col0 & 1023;
  const _Float16* wtg = wt + (size_t)g * (1024 * 1024);
  const int tid = threadIdx.x;
  const int lane = tid & 63;
  const int w = tid >> 6;
  const int wm = w >> 2, wn = w & 3;  // wave tile: rows [wm*128,+128), cols [wn*64,+64)
  const int l15 = lane & 15, l4 = lane >> 4;

  int srow[2], scol[2], dst[2];
#pragma unroll
  for (int i = 0; i < 2; ++i) {
    int u = i * 512 + tid;
    int rb = u >> 6, rr = (u >> 2) & 15, ccb = u & 3;
    srow[i] = rb * 16 + rr;
    scol[i] = (ccb * 8) ^ ((rr & 8) ? 16 : 0);  // pre-swizzled source col
    dst[i] = u * 8;
  }
  const int kx = (l4 * 8) ^ ((l15 & 8) ? 16 : 0);

  auto stageA = [&](int b, int kt) {
#pragma unroll
    for (int i = 0; i < 2; ++i)
      gload16(xh + (size_t)(row0 + srow[i]) * 1024 + kt * 32 + scol[i], &As[b][dst[i]]);
  };
  auto stageB = [&](int b, int kt) {
#pragma unroll
    for (int i = 0; i < 2; ++i)
      gload16(wtg + (size_t)(col0g + srow[i]) * 1024 + kt * 32 + scol[i], &Bs[b][dst[i]]);
  };

  f32x4 acc[8][4] = {};

  stageA(0, 0); stageB(0, 0);
  stageA(1, 1); stageB(1, 1);

  int b = 0;
  for (int kt = 0; kt < 32; ++kt) {
    int b2 = b + 2; if (b2 >= 3) b2 -= 3;
    if (kt < 30) stageA(b2, kt + 2);
    if (kt < 30)       asm volatile("s_waitcnt vmcnt(6)" ::: "memory");
    else if (kt == 30) asm volatile("s_waitcnt vmcnt(4)" ::: "memory");
    else               asm volatile("s_waitcnt vmcnt(0)" ::: "memory");
    asm volatile("s_barrier" ::: "memory");  // single barrier per K-tile

    const _Float16* Ab = &As[b][0];
    const _Float16* Bb = &Bs[b][0];
    half8 av[4], bv[4];
#pragma unroll
    for (int mi = 0; mi < 4; ++mi)
      av[mi] = *(const half8*)&Ab[(wm * 8 + mi) * 512 + l15 * 32 + kx];
#pragma unroll
    for (int ni = 0; ni < 4; ++ni)
      bv[ni] = *(const half8*)&Bb[(wn * 4 + ni) * 512 + l15 * 32 + kx];
    if (kt < 30) stageB(b2, kt + 2);
    __builtin_amdgcn_s_setprio(1);
#pragma unroll
    for (int mi = 0; mi < 4; ++mi)
#pragma unroll
      for (int ni = 0; ni < 4; ++ni)
        acc[mi][ni] = __builtin_amdgcn_mfma_f32_16x16x32_f16(av[mi], bv[ni], acc[mi][ni], 0, 0, 0);
    __builtin_amdgcn_s_setprio(0);

    half8 av2[4];
#pragma unroll
    for (int mi = 0; mi < 4; ++mi)
      av2[mi] = *(const half8*)&Ab[(wm * 8 + 4 + mi) * 512 + l15 * 32 + kx];
    __builtin_amdgcn_s_setprio(1);
#pragma unroll
    for (int mi = 0; mi < 4; ++mi)
#pragma unroll
      for (int ni = 0; ni < 4; ++ni)
        acc[4 + mi][ni] = __builtin_amdgcn_mfma_f32_16x16x32_f16(av2[mi], bv[ni], acc[4 + mi][ni], 0, 0, 0);
    __builtin_amdgcn_s_setprio(0);

    b = b + 1; if (b == 3) b = 0;
  }

  if (g < 2) {
    // Q/K epilogue: C row = (lane>>4)*4+reg, col = lane&15; fp16 bits
#pragma unroll
    for (int mi = 0; mi < 8; ++mi) {
      int gr0 = row0 + wm * 128 + mi * 16 + l4 * 4;
#pragma unroll
      for (int ni = 0; ni < 4; ++ni) {
        int gc = col0 + wn * 64 + ni * 16 + l15;
#pragma unroll
        for (int r = 0; r < 4; ++r)
          qkv[(size_t)(gr0 + r) * QKV_LD + gc] =
              __builtin_bit_cast(ushort_t, (_Float16)acc[mi][ni][r]);
      }
    }
  } else {
    // V epilogue: transpose 256n x 256c through LDS, write vT[bh][d][n] bf16.
    const int b_ = row0 >> 12;      // batch
    const int n0_ = row0 & 4095;    // n base
#pragma unroll 1
    for (int p = 0; p < 4; ++p) {   // pass covers n in [p*64, p*64+64)
      __syncthreads();              // T free (K-loop LDS reads / prev pass done)
      if (wm == (p >> 1)) {
        const int mi0 = (p & 1) * 4;
#pragma unroll
        for (int mi4 = 0; mi4 < 4; ++mi4) {
#pragma unroll
          for (int ni = 0; ni < 4; ++ni) {
            int c = wn * 64 + ni * 16 + l15;
#pragma unroll
            for (int r = 0; r < 4; ++r)
              T[c][mi4 * 16 + l4 * 4 + r] = f2bf(acc[mi0 + mi4][ni][r]);
          }
        }
      }
      __syncthreads();
      // cooperative write: 256 c-rows x 64 n
#pragma unroll
      for (int i = 0; i < 4; ++i) {
        int u = i * 512 + tid;
        int c = u >> 3, nc = (u & 7) * 8;
        int h = (col0g + c) >> 6, d = c & 63;
        short8 v = *(const short8*)&T[c][nc];
        *(short8*)(vT + ((size_t)((b_ * 16 + h) * 64 + d)) * 4096 + n0_ + p * 64 + nc) = v;
      }
    }
  }
}

// ---------------- fused phi(k) + kv accumulation ----------------
__global__ __launch_bounds__(256) void k_kv(const ushort_t* __restrict__ qkv,
                                            const ushort_t* __restrict__ vT,
                                            const _Float16* __restrict__ om,
                                            float* __restrict__ kv,
                                            float* __restrict__ pksum) {
  __shared__ _Float16 kt[64][72];
  __shared__ ushort_t vt[64][72];
  __shared__ ushort_t pk[256][72];  // [m][n], rows 144B
  __shared__ float nrm[64];
  const int bh = blockIdx.x, split = blockIdx.y;
  const int b = bh >> 4, h = bh & 15;
  const int tid = threadIdx.x, lane = tid & 63, w = tid >> 6;
  const int l15 = lane & 15, l4 = lane >> 4;

  half8 bom[4][2];
#pragma unroll
  for (int mf = 0; mf < 4; ++mf)
#pragma unroll
    for (int ks = 0; ks < 2; ++ks)
      bom[mf][ks] = *(const half8*)(om + (size_t)(w * 64 + mf * 16 + l15) * 64 + ks * 32 + l4 * 8);

  f32x4 kvacc[4][4] = {};
  float psum[4] = {0.f, 0.f, 0.f, 0.f};

  for (int ch = 0; ch < 8; ++ch) {
    const int nbase = split * 512 + ch * 64;
#pragma unroll
    for (int i = 0; i < 2; ++i) {
      int c = i * 256 + tid;
      int r = c >> 3, s = c & 7;
      *(short8*)&kt[r][s * 8] =
          *(const short8*)(qkv + (size_t)(b * 4096 + nbase + r) * QKV_LD + 1024 + h * 64 + s * 8);
      *(short8*)&vt[r][s * 8] =
          *(const short8*)(vT + (size_t)(bh * 64 + r) * 4096 + nbase + s * 8);
    }
    __syncthreads();
    {
      int row = tid >> 2, part = tid & 3;
      float sm = 0.f;
#pragma unroll
      for (int i = 0; i < 16; ++i) {
        float kf = (float)kt[row][part * 16 + i];
        sm += kf * kf;
      }
      sm += __shfl_xor(sm, 1);
      sm += __shfl_xor(sm, 2);
      if ((tid & 3) == 0) nrm[row] = 0.5f * sm;
    }
    __syncthreads();
#pragma unroll
    for (int nf = 0; nf < 4; ++nf) {
      half8 a0 = *(const half8*)&kt[nf * 16 + l15][l4 * 8];
      half8 a1 = *(const half8*)&kt[nf * 16 + l15][32 + l4 * 8];
#pragma unroll
      for (int mf = 0; mf < 4; ++mf) {
        f32x4 f = {};
        f = __builtin_amdgcn_mfma_f32_16x16x32_f16(a0, bom[mf][0], f, 0, 0, 0);
        f = __builtin_amdgcn_mfma_f32_16x16x32_f16(a1, bom[mf][1], f, 0, 0, 0);
        ushort4v pw;
#pragma unroll
        for (int r = 0; r < 4; ++r) {
          int n = nf * 16 + l4 * 4 + r;
          float p = __expf(f[r] - nrm[n]) * 0.0625f;
          psum[mf] += p;
          pw[r] = f2bf(p);
        }
        *(ushort4v*)&pk[w * 64 + mf * 16 + l15][nf * 16 + l4 * 4] = pw;
      }
    }
    __syncthreads();
#pragma unroll
    for (int ks = 0; ks < 2; ++ks) {
      short8 pa[4];
#pragma unroll
      for (int mf = 0; mf < 4; ++mf)
        pa[mf] = *(const short8*)&pk[w * 64 + mf * 16 + l15][ks * 32 + l4 * 8];
#pragma unroll
      for (int df = 0; df < 4; ++df) {
        short8 bv = *(const short8*)&vt[df * 16 + l15][ks * 32 + l4 * 8];
#pragma unroll
        for (int mf = 0; mf < 4; ++mf)
          kvacc[mf][df] = __builtin_amdgcn_mfma_f32_16x16x32_bf16(pa[mf], bv, kvacc[mf][df], 0, 0, 0);
      }
    }
    __syncthreads();
  }
#pragma unroll
  for (int mf = 0; mf < 4; ++mf)
#pragma unroll
    for (int df = 0; df < 4; ++df)
#pragma unroll
      for (int r = 0; r < 4; ++r) {
        int m = w * 64 + mf * 16 + l4 * 4 + r;
        int d = df * 16 + l15;
        atomicAdd(&kv[((size_t)bh * 256 + m) * 64 + d], kvacc[mf][df][r]);
      }
#pragma unroll
  for (int mf = 0; mf < 4; ++mf) {
    float v = psum[mf];
    v += __shfl_xor(v, 16);
    v += __shfl_xor(v, 32);
    if (lane < 16) atomicAdd(&pksum[bh * 256 + w * 64 + mf * 16 + lane], v);
  }
}

// ---------------- kv -> kvt (B^T bf16, + pksum row 64, zero pad rows) ----------------
__global__ __launch_bounds__(256) void k_kvt(const float* __restrict__ kv,
                                             const float* __restrict__ pksum,
                                             ushort_t* __restrict__ kvt) {
  const int bh = blockIdx.x, tid = threadIdx.x;
  const int d = tid >> 2, mb = (tid & 3) * 64;
  for (int j = 0; j < 64; ++j) {
    int m = mb + j;
    kvt[((size_t)bh * 80 + d) * 256 + m] = f2bf(kv[((size_t)bh * 256 + m) * 64 + d]);
  }
  kvt[((size_t)bh * 80 + 64) * 256 + tid] = f2bf(pksum[bh * 256 + tid]);
  for (int r = 65; r < 80; ++r) kvt[((size_t)bh * 80 + r) * 256 + tid] = 0;
}

// ---------------- fused phi(q) + out (LDS-resident, reg-omega) ----------------
__global__ __launch_bounds__(512) void k_out(const ushort_t* __restrict__ qkv,
                                             const ushort_t* __restrict__ kvt,
                                             const _Float16* __restrict__ om,
                                             float* __restrict__ outp) {
  __shared__ ushort_t kvl[80][264];
  __shared__ _Float16 qt[128][72];
  __shared__ ushort_t pq[128][264];  // pq^T: [n][m]
  __shared__ float nrm[128];
  const int bh = blockIdx.x, ns = blockIdx.y;
  const int b = bh >> 4, h = bh & 15;
  const int tid = threadIdx.x, lane = tid & 63, w = tid >> 6;
  const int l15 = lane & 15, l4 = lane >> 4;
  const int wn = w >> 2, wm = w & 3;

#pragma unroll
  for (int i = 0; i < 5; ++i) {
    int u = i * 512 + tid;
    int r = u >> 5, c = (u & 31) * 8;
    *(short8*)&kvl[r][c] = *(const short8*)(kvt + ((size_t)bh * 80 + r) * 256 + c);
  }
  half8 bom[4][2];
#pragma unroll
  for (int mf = 0; mf < 4; ++mf)
#pragma unroll
    for (int ks = 0; ks < 2; ++ks)
      bom[mf][ks] = *(const half8*)(om + (size_t)(wm * 64 + mf * 16 + l15) * 64 + ks * 32 + l4 * 8);

  for (int ch = 0; ch < 4; ++ch) {
    const int n0 = ns * 512 + ch * 128;
#pragma unroll
    for (int i = 0; i < 2; ++i) {
      int u = i * 512 + tid;
      int r = u >> 3, s = (u & 7) * 8;
      *(half8*)&qt[r][s] =
          *(const half8*)((const _Float16*)qkv + (size_t)(b * 4096 + n0 + r) * QKV_LD + h * 64 + s);
    }
    __syncthreads();
    {
      int row = tid >> 2, part = tid & 3;
      float sm = 0.f;
#pragma unroll
      for (int i = 0; i < 16; ++i) {
        float qf = (float)qt[row][part * 16 + i];
        sm += qf * qf;
      }
      sm += __shfl_xor(sm, 1);
      sm += __shfl_xor(sm, 2);
      if ((tid & 3) == 0) nrm[row] = 0.5f * sm;
    }
    __syncthreads();
#pragma unroll
    for (int nf = 0; nf < 4; ++nf) {
      half8 qa0 = *(const half8*)&qt[wn * 64 + nf * 16 + l15][l4 * 8];
      half8 qa1 = *(const half8*)&qt[wn * 64 + nf * 16 + l15][32 + l4 * 8];
      float nr = nrm[wn * 64 + nf * 16 + l15];
#pragma unroll
      for (int mf = 0; mf < 4; ++mf) {
        f32x4 f = {};
        f = __builtin_amdgcn_mfma_f32_16x16x32_f16(bom[mf][0], qa0, f, 0, 0, 0);
        f = __builtin_amdgcn_mfma_f32_16x16x32_f16(bom[mf][1], qa1, f, 0, 0, 0);
        ushort4v pw;
#pragma unroll
        for (int r = 0; r < 4; ++r) {
          float p = __expf(f[r] - nr) * 0.0625f;
          pw[r] = f2bf(p);
        }
        *(ushort4v*)&pq[wn * 64 + nf * 16 + l15][wm * 64 + mf * 16 + l4 * 4] = pw;
      }
    }
    __syncthreads();
    f32x4 oacc[5] = {};
#pragma unroll
    for (int ks = 0; ks < 8; ++ks) {
      short8 pa = *(const short8*)&pq[w * 16 + l15][ks * 32 + l4 * 8];
#pragma unroll
      for (int cf = 0; cf < 5; ++cf) {
        short8 bv = *(const short8*)&kvl[cf * 16 + l15][ks * 32 + l4 * 8];
        oacc[cf] = __builtin_amdgcn_mfma_f32_16x16x32_bf16(pa, bv, oacc[cf], 0, 0, 0);
      }
    }
#pragma unroll
    for (int r = 0; r < 4; ++r) {
      float z = __shfl(oacc[4][r], lane & 48);
      float inv = 1.0f / (z + 1e-6f);
      int n = n0 + w * 16 + l4 * 4 + r;
#pragma unroll
      for (int cf = 0; cf < 4; ++cf)
        outp[(size_t)(b * 4096 + n) * 1024 + h * 64 + cf * 16 + l15] = oacc[cf][r] * inv;
    }
  }
}

extern "C" void kernel_launch(void* const* d_in, const int* in_sizes, int n_in,
                              void* d_out, int out_size, void* d_ws, size_t ws_size,
                              hipStream_t stream) {
  const float* x = (const float*)d_in[0];
  const float* Wq = (const float*)d_in[1];
  const float* Wk = (const float*)d_in[2];
  const float* Wv = (const float*)d_in[3];
  const float* omg = (const float*)d_in[4];
  float* outp = (float*)d_out;
  char* ws = (char*)d_ws;

  // ws layout (bytes), total 147,423,232 (~141 MB)
  _Float16* wt = (_Float16*)(ws);                 // 6,291,456
  _Float16* om = (_Float16*)(ws + 6291456);       //    32,768
  ushort_t* qkv = (ushort_t*)(ws + 6324224);      // 67,108,864 (Q|K, stride 2048)
  ushort_t* vT = (ushort_t*)(ws + 73433088);      // 33,554,432
  _Float16* xh = (_Float16*)(ws + 106987520);     // 33,554,432
  float* kv = (float*)(ws + 140541952);           // 4,194,304
  float* pksum = (float*)(ws + 144736256);        //    65,536
  ushort_t* kvt = (ushort_t*)(ws + 144801792);    // 2,621,440

  k_wtrans<<<dim3(32, 32, 3), dim3(32, 8), 0, stream>>>(Wq, Wk, Wv, wt);
  k_omconv<<<dim3(64), dim3(256), 0, stream>>>(omg, om);
  k_xconv<<<dim3(8192), dim3(256), 0, stream>>>(x, xh);
  k_gemm<<<dim3(768), dim3(512), 0, stream>>>(xh, wt, qkv, vT);
  hipMemsetAsync(kv, 0, 4194304 + 65536, stream);  // kv + pksum (contiguous)
  k_kv<<<dim3(64, 8), dim3(256), 0, stream>>>(qkv, vT, om, kv, pksum);
  k_kvt<<<dim3(64), dim3(256), 0, stream>>>(kv, pksum, kvt);
  k_out<<<dim3(64, 8), dim3(512), 0, stream>>>(qkv, kvt, om, outp);
}

// Round 6
// 251.265 us; speedup vs baseline: 1.3200x; 1.3200x over previous
//
#include <hip/hip_runtime.h>

// Performer (FAVOR+) attention, MI355X.
// B=4 N=4096 H=16 D=64 DIM=1024 M=256.
// Pipeline:
//  k_wtrans:  W[k][n] f32 -> wt[g][n][k] fp16   (B^T layout for MFMA)
//  k_omconv:  omega f32 -> fp16
//  k_xconv:   x f32 -> xh fp16
//  k_gemm:    Q,K -> qkv (stride 2048, fp16); V -> transposed in-epilogue to
//             vT[bh][d][n] bf16. 256x256 tile, BK=32, RING-4 LDS (race-free:
//             stage target (kt+2)&3 disjoint from reader bufs kt&3,(kt+3)&3),
//             counted vmcnt(6), one s_barrier/K-tile, setprio, XOR swizzle.
//             V-transpose T aliases As (dead after K-loop); p-loop FULLY
//             unrolled (rule #20: no runtime acc indexing -> no scratch).
//  k_kv:      pk = exp(k.om^T - |k|^2/2)/16 ; kv += pk^T v ; pksum
//  k_kvt:     kvt[bh][j][m] bf16: rows 0..63 = kv^T, row 64 = pksum, 65..79 = 0
//  k_out:     kvt staged in LDS once/block, omega in registers,
//             swapped proj mfma(om, q) -> pq^T b64 LDS writes, PV all-LDS.

typedef _Float16 half8 __attribute__((ext_vector_type(8)));
typedef short short8 __attribute__((ext_vector_type(8)));
typedef float f32x4 __attribute__((ext_vector_type(4)));
typedef unsigned short ushort4v __attribute__((ext_vector_type(4)));
typedef unsigned short ushort_t;
typedef unsigned int uint_t;

#define QKV_LD 2048

__device__ __forceinline__ ushort_t f2bf(float f) {
  uint_t u = __builtin_bit_cast(uint_t, f);
  u += 0x7fffu + ((u >> 16) & 1u);
  return (ushort_t)(u >> 16);
}

__device__ __forceinline__ void gload16(const void* g, void* l) {
  __builtin_amdgcn_global_load_lds(
      (const __attribute__((address_space(1))) void*)g,
      (__attribute__((address_space(3))) void*)l, 16, 0, 0);
}

// ---------------- W transpose+convert: wt[g][n][k] = (f16)W_g[k][n] ----------------
__global__ void k_wtrans(const float* __restrict__ Wq, const float* __restrict__ Wk,
                         const float* __restrict__ Wv, _Float16* __restrict__ wt) {
  __shared__ float t[32][33];
  const int g = blockIdx.z;
  const float* W = (g == 0) ? Wq : ((g == 1) ? Wk : Wv);
  const int n0 = blockIdx.x * 32, k0 = blockIdx.y * 32;
  const int tx = threadIdx.x, ty = threadIdx.y;
#pragma unroll
  for (int j = 0; j < 4; ++j)
    t[ty + j * 8][tx] = W[(size_t)(k0 + ty + j * 8) * 1024 + n0 + tx];
  __syncthreads();
  _Float16* o = wt + (size_t)g * 1024 * 1024;
#pragma unroll
  for (int j = 0; j < 4; ++j)
    o[(size_t)(n0 + ty + j * 8) * 1024 + k0 + tx] = (_Float16)t[tx][ty + j * 8];
}

__global__ void k_omconv(const float* __restrict__ omega, _Float16* __restrict__ om) {
  int i = blockIdx.x * 256 + threadIdx.x;
  if (i < 16384) om[i] = (_Float16)omega[i];
}

// ---------------- x convert: xh[n][k] = (f16)x[n][k] ----------------
__global__ __launch_bounds__(256) void k_xconv(const float* __restrict__ x,
                                               _Float16* __restrict__ xh) {
  size_t base = ((size_t)blockIdx.x * 256 + threadIdx.x) * 8;
  float4 f0 = *(const float4*)(x + base);
  float4 f1 = *(const float4*)(x + base + 4);
  half8 h;
  h[0] = (_Float16)f0.x; h[1] = (_Float16)f0.y; h[2] = (_Float16)f0.z; h[3] = (_Float16)f0.w;
  h[4] = (_Float16)f1.x; h[5] = (_Float16)f1.y; h[6] = (_Float16)f1.z; h[7] = (_Float16)f1.w;
  *(half8*)(xh + base) = h;
}

// ---------------- QKV GEMM: 256x256 tile, BK=32, ring-4, 1 barrier/K-tile ----------------
__global__ __launch_bounds__(512, 2) void k_gemm(const _Float16* __restrict__ xh,
                                                 const _Float16* __restrict__ wt,
                                                 ushort_t* __restrict__ qkv,
                                                 ushort_t* __restrict__ vT) {
  __shared__ _Float16 As[4][8192];  // 64 KB; T (36 KB) aliases As[0..1] in epilogue
  __shared__ _Float16 Bs[4][8192];  // 64 KB
  const int vb = (blockIdx.x & 7) * 96 + (blockIdx.x >> 3);
  const int ct = vb % 12, rt = vb / 12;
  const int col0 = ct * 256, row0 = rt * 256;
  const int g = col0 >> 10;  // 0=Q 1=K 2=V
  const int col0g = col0 & 1023;
  const _Float16* wtg = wt + (size_t)g * (1024 * 1024);
  const int tid = threadIdx.x;
  const int lane = tid & 63;
  const int w = tid >> 6;
  const int wm = w >> 2, wn = w & 3;  // wave tile: rows [wm*128,+128), cols [wn*64,+64)
  const int l15 = lane & 15, l4 = lane >> 4;

  int srow[2], scol[2], dst[2];
#pragma unroll
  for (int i = 0; i < 2; ++i) {
    int u = i * 512 + tid;
    int rb = u >> 6, rr = (u >> 2) & 15, ccb = u & 3;
    srow[i] = rb * 16 + rr;
    scol[i] = (ccb * 8) ^ ((rr & 8) ? 16 : 0);  // pre-swizzled source col
    dst[i] = u * 8;
  }
  const int kx = (l4 * 8) ^ ((l15 & 8) ? 16 : 0);

  auto stageA = [&](int b, int kt) {
#pragma unroll
    for (int i = 0; i < 2; ++i)
      gload16(xh + (size_t)(row0 + srow[i]) * 1024 + kt * 32 + scol[i], &As[b][dst[i]]);
  };
  auto stageB = [&](int b, int kt) {
#pragma unroll
    for (int i = 0; i < 2; ++i)
      gload16(wtg + (size_t)(col0g + srow[i]) * 1024 + kt * 32 + scol[i], &Bs[b][dst[i]]);
  };

  f32x4 acc[8][4] = {};

  stageA(0, 0); stageB(0, 0);
  stageA(1, 1); stageB(1, 1);

  for (int kt = 0; kt < 32; ++kt) {
    const int b = kt & 3, b2 = (kt + 2) & 3;
    if (kt < 30) stageA(b2, kt + 2);
    if (kt < 30)       asm volatile("s_waitcnt vmcnt(6)" ::: "memory");
    else if (kt == 30) asm volatile("s_waitcnt vmcnt(4)" ::: "memory");
    else               asm volatile("s_waitcnt vmcnt(0)" ::: "memory");
    asm volatile("s_barrier" ::: "memory");  // single barrier per K-tile

    const _Float16* Ab = &As[b][0];
    const _Float16* Bb = &Bs[b][0];
    half8 av[4], bv[4];
#pragma unroll
    for (int mi = 0; mi < 4; ++mi)
      av[mi] = *(const half8*)&Ab[(wm * 8 + mi) * 512 + l15 * 32 + kx];
#pragma unroll
    for (int ni = 0; ni < 4; ++ni)
      bv[ni] = *(const half8*)&Bb[(wn * 4 + ni) * 512 + l15 * 32 + kx];
    if (kt < 30) stageB(b2, kt + 2);
    __builtin_amdgcn_s_setprio(1);
#pragma unroll
    for (int mi = 0; mi < 4; ++mi)
#pragma unroll
      for (int ni = 0; ni < 4; ++ni)
        acc[mi][ni] = __builtin_amdgcn_mfma_f32_16x16x32_f16(av[mi], bv[ni], acc[mi][ni], 0, 0, 0);
    __builtin_amdgcn_s_setprio(0);

    half8 av2[4];
#pragma unroll
    for (int mi = 0; mi < 4; ++mi)
      av2[mi] = *(const half8*)&Ab[(wm * 8 + 4 + mi) * 512 + l15 * 32 + kx];
    __builtin_amdgcn_s_setprio(1);
#pragma unroll
    for (int mi = 0; mi < 4; ++mi)
#pragma unroll
      for (int ni = 0; ni < 4; ++ni)
        acc[4 + mi][ni] = __builtin_amdgcn_mfma_f32_16x16x32_f16(av2[mi], bv[ni], acc[4 + mi][ni], 0, 0, 0);
    __builtin_amdgcn_s_setprio(0);
  }

  if (g < 2) {
    // Q/K epilogue: C row = (lane>>4)*4+reg, col = lane&15; fp16 bits
#pragma unroll
    for (int mi = 0; mi < 8; ++mi) {
      int gr0 = row0 + wm * 128 + mi * 16 + l4 * 4;
#pragma unroll
      for (int ni = 0; ni < 4; ++ni) {
        int gc = col0 + wn * 64 + ni * 16 + l15;
#pragma unroll
        for (int r = 0; r < 4; ++r)
          qkv[(size_t)(gr0 + r) * QKV_LD + gc] =
              __builtin_bit_cast(ushort_t, (_Float16)acc[mi][ni][r]);
      }
    }
  } else {
    // V epilogue: transpose 256n x 256c through LDS (aliasing As), write vT bf16.
    ushort_t(*T)[72] = reinterpret_cast<ushort_t(*)[72]>(&As[0][0]);
    const int b_ = row0 >> 12;    // batch
    const int n0_ = row0 & 4095;  // n base
#pragma unroll
    for (int p = 0; p < 4; ++p) {  // pass covers n in [p*64, p*64+64); FULL unroll
      __syncthreads();             // K-loop / prev-pass LDS reads complete
      if (wm == (p >> 1)) {
        const int mi0 = (p & 1) * 4;
#pragma unroll
        for (int mi4 = 0; mi4 < 4; ++mi4) {
#pragma unroll
          for (int ni = 0; ni < 4; ++ni) {
            int c = wn * 64 + ni * 16 + l15;
            ushort4v tv;
#pragma unroll
            for (int r = 0; r < 4; ++r) tv[r] = f2bf(acc[mi0 + mi4][ni][r]);
            *(ushort4v*)&T[c][mi4 * 16 + l4 * 4] = tv;
          }
        }
      }
      __syncthreads();
      // cooperative write: 256 c-rows x 64 n
#pragma unroll
      for (int i = 0; i < 4; ++i) {
        int u = i * 512 + tid;
        int c = u >> 3, nc = (u & 7) * 8;
        int h = (col0g + c) >> 6, d = c & 63;
        short8 v = *(const short8*)&T[c][nc];
        *(short8*)(vT + ((size_t)((b_ * 16 + h) * 64 + d)) * 4096 + n0_ + p * 64 + nc) = v;
      }
    }
  }
}

// ---------------- fused phi(k) + kv accumulation ----------------
__global__ __launch_bounds__(256) void k_kv(const ushort_t* __restrict__ qkv,
                                            const ushort_t* __restrict__ vT,
                                            const _Float16* __restrict__ om,
                                            float* __restrict__ kv,
                                            float* __restrict__ pksum) {
  __shared__ _Float16 kt[64][72];
  __shared__ ushort_t vt[64][72];
  __shared__ ushort_t pk[256][72];  // [m][n], rows 144B
  __shared__ float nrm[64];
  const int bh = blockIdx.x, split = blockIdx.y;
  const int b = bh >> 4, h = bh & 15;
  const int tid = threadIdx.x, lane = tid & 63, w = tid >> 6;
  const int l15 = lane & 15, l4 = lane >> 4;

  half8 bom[4][2];
#pragma unroll
  for (int mf = 0; mf < 4; ++mf)
#pragma unroll
    for (int ks = 0; ks < 2; ++ks)
      bom[mf][ks] = *(const half8*)(om + (size_t)(w * 64 + mf * 16 + l15) * 64 + ks * 32 + l4 * 8);

  f32x4 kvacc[4][4] = {};
  float psum[4] = {0.f, 0.f, 0.f, 0.f};

  for (int ch = 0; ch < 8; ++ch) {
    const int nbase = split * 512 + ch * 64;
#pragma unroll
    for (int i = 0; i < 2; ++i) {
      int c = i * 256 + tid;
      int r = c >> 3, s = c & 7;
      *(short8*)&kt[r][s * 8] =
          *(const short8*)(qkv + (size_t)(b * 4096 + nbase + r) * QKV_LD + 1024 + h * 64 + s * 8);
      *(short8*)&vt[r][s * 8] =
          *(const short8*)(vT + (size_t)(bh * 64 + r) * 4096 + nbase + s * 8);
    }
    __syncthreads();
    {
      int row = tid >> 2, part = tid & 3;
      float sm = 0.f;
#pragma unroll
      for (int i = 0; i < 16; ++i) {
        float kf = (float)kt[row][part * 16 + i];
        sm += kf * kf;
      }
      sm += __shfl_xor(sm, 1);
      sm += __shfl_xor(sm, 2);
      if ((tid & 3) == 0) nrm[row] = 0.5f * sm;
    }
    __syncthreads();
#pragma unroll
    for (int nf = 0; nf < 4; ++nf) {
      half8 a0 = *(const half8*)&kt[nf * 16 + l15][l4 * 8];
      half8 a1 = *(const half8*)&kt[nf * 16 + l15][32 + l4 * 8];
#pragma unroll
      for (int mf = 0; mf < 4; ++mf) {
        f32x4 f = {};
        f = __builtin_amdgcn_mfma_f32_16x16x32_f16(a0, bom[mf][0], f, 0, 0, 0);
        f = __builtin_amdgcn_mfma_f32_16x16x32_f16(a1, bom[mf][1], f, 0, 0, 0);
        ushort4v pw;
#pragma unroll
        for (int r = 0; r < 4; ++r) {
          int n = nf * 16 + l4 * 4 + r;
          float p = __expf(f[r] - nrm[n]) * 0.0625f;
          psum[mf] += p;
          pw[r] = f2bf(p);
        }
        *(ushort4v*)&pk[w * 64 + mf * 16 + l15][nf * 16 + l4 * 4] = pw;
      }
    }
    __syncthreads();
#pragma unroll
    for (int ks = 0; ks < 2; ++ks) {
      short8 pa[4];
#pragma unroll
      for (int mf = 0; mf < 4; ++mf)
        pa[mf] = *(const short8*)&pk[w * 64 + mf * 16 + l15][ks * 32 + l4 * 8];
#pragma unroll
      for (int df = 0; df < 4; ++df) {
        short8 bv = *(const short8*)&vt[df * 16 + l15][ks * 32 + l4 * 8];
#pragma unroll
        for (int mf = 0; mf < 4; ++mf)
          kvacc[mf][df] = __builtin_amdgcn_mfma_f32_16x16x32_bf16(pa[mf], bv, kvacc[mf][df], 0, 0, 0);
      }
    }
    __syncthreads();
  }
#pragma unroll
  for (int mf = 0; mf < 4; ++mf)
#pragma unroll
    for (int df = 0; df < 4; ++df)
#pragma unroll
      for (int r = 0; r < 4; ++r) {
        int m = w * 64 + mf * 16 + l4 * 4 + r;
        int d = df * 16 + l15;
        atomicAdd(&kv[((size_t)bh * 256 + m) * 64 + d], kvacc[mf][df][r]);
      }
#pragma unroll
  for (int mf = 0; mf < 4; ++mf) {
    float v = psum[mf];
    v += __shfl_xor(v, 16);
    v += __shfl_xor(v, 32);
    if (lane < 16) atomicAdd(&pksum[bh * 256 + w * 64 + mf * 16 + lane], v);
  }
}

// ---------------- kv -> kvt (B^T bf16, + pksum row 64, zero pad rows) ----------------
__global__ __launch_bounds__(256) void k_kvt(const float* __restrict__ kv,
                                             const float* __restrict__ pksum,
                                             ushort_t* __restrict__ kvt) {
  const int bh = blockIdx.x, tid = threadIdx.x;
  const int d = tid >> 2, mb = (tid & 3) * 64;
  for (int j = 0; j < 64; ++j) {
    int m = mb + j;
    kvt[((size_t)bh * 80 + d) * 256 + m] = f2bf(kv[((size_t)bh * 256 + m) * 64 + d]);
  }
  kvt[((size_t)bh * 80 + 64) * 256 + tid] = f2bf(pksum[bh * 256 + tid]);
  for (int r = 65; r < 80; ++r) kvt[((size_t)bh * 80 + r) * 256 + tid] = 0;
}

// ---------------- fused phi(q) + out (LDS-resident, reg-omega) ----------------
__global__ __launch_bounds__(512) void k_out(const ushort_t* __restrict__ qkv,
                                             const ushort_t* __restrict__ kvt,
                                             const _Float16* __restrict__ om,
                                             float* __restrict__ outp) {
  __shared__ ushort_t kvl[80][264];
  __shared__ _Float16 qt[128][72];
  __shared__ ushort_t pq[128][264];  // pq^T: [n][m]
  __shared__ float nrm[128];
  const int bh = blockIdx.x, ns = blockIdx.y;
  const int b = bh >> 4, h = bh & 15;
  const int tid = threadIdx.x, lane = tid & 63, w = tid >> 6;
  const int l15 = lane & 15, l4 = lane >> 4;
  const int wn = w >> 2, wm = w & 3;

#pragma unroll
  for (int i = 0; i < 5; ++i) {
    int u = i * 512 + tid;
    int r = u >> 5, c = (u & 31) * 8;
    *(short8*)&kvl[r][c] = *(const short8*)(kvt + ((size_t)bh * 80 + r) * 256 + c);
  }
  half8 bom[4][2];
#pragma unroll
  for (int mf = 0; mf < 4; ++mf)
#pragma unroll
    for (int ks = 0; ks < 2; ++ks)
      bom[mf][ks] = *(const half8*)(om + (size_t)(wm * 64 + mf * 16 + l15) * 64 + ks * 32 + l4 * 8);

  for (int ch = 0; ch < 4; ++ch) {
    const int n0 = ns * 512 + ch * 128;
#pragma unroll
    for (int i = 0; i < 2; ++i) {
      int u = i * 512 + tid;
      int r = u >> 3, s = (u & 7) * 8;
      *(half8*)&qt[r][s] =
          *(const half8*)((const _Float16*)qkv + (size_t)(b * 4096 + n0 + r) * QKV_LD + h * 64 + s);
    }
    __syncthreads();
    {
      int row = tid >> 2, part = tid & 3;
      float sm = 0.f;
#pragma unroll
      for (int i = 0; i < 16; ++i) {
        float qf = (float)qt[row][part * 16 + i];
        sm += qf * qf;
      }
      sm += __shfl_xor(sm, 1);
      sm += __shfl_xor(sm, 2);
      if ((tid & 3) == 0) nrm[row] = 0.5f * sm;
    }
    __syncthreads();
#pragma unroll
    for (int nf = 0; nf < 4; ++nf) {
      half8 qa0 = *(const half8*)&qt[wn * 64 + nf * 16 + l15][l4 * 8];
      half8 qa1 = *(const half8*)&qt[wn * 64 + nf * 16 + l15][32 + l4 * 8];
      float nr = nrm[wn * 64 + nf * 16 + l15];
#pragma unroll
      for (int mf = 0; mf < 4; ++mf) {
        f32x4 f = {};
        f = __builtin_amdgcn_mfma_f32_16x16x32_f16(bom[mf][0], qa0, f, 0, 0, 0);
        f = __builtin_amdgcn_mfma_f32_16x16x32_f16(bom[mf][1], qa1, f, 0, 0, 0);
        ushort4v pw;
#pragma unroll
        for (int r = 0; r < 4; ++r) {
          float p = __expf(f[r] - nr) * 0.0625f;
          pw[r] = f2bf(p);
        }
        *(ushort4v*)&pq[wn * 64 + nf * 16 + l15][wm * 64 + mf * 16 + l4 * 4] = pw;
      }
    }
    __syncthreads();
    f32x4 oacc[5] = {};
#pragma unroll
    for (int ks = 0; ks < 8; ++ks) {
      short8 pa = *(const short8*)&pq[w * 16 + l15][ks * 32 + l4 * 8];
#pragma unroll
      for (int cf = 0; cf < 5; ++cf) {
        short8 bv = *(const short8*)&kvl[cf * 16 + l15][ks * 32 + l4 * 8];
        oacc[cf] = __builtin_amdgcn_mfma_f32_16x16x32_bf16(pa, bv, oacc[cf], 0, 0, 0);
      }
    }
#pragma unroll
    for (int r = 0; r < 4; ++r) {
      float z = __shfl(oacc[4][r], lane & 48);
      float inv = 1.0f / (z + 1e-6f);
      int n = n0 + w * 16 + l4 * 4 + r;
#pragma unroll
      for (int cf = 0; cf < 4; ++cf)
        outp[(size_t)(b * 4096 + n) * 1024 + h * 64 + cf * 16 + l15] = oacc[cf][r] * inv;
    }
  }
}

extern "C" void kernel_launch(void* const* d_in, const int* in_sizes, int n_in,
                              void* d_out, int out_size, void* d_ws, size_t ws_size,
                              hipStream_t stream) {
  const float* x = (const float*)d_in[0];
  const float* Wq = (const float*)d_in[1];
  const float* Wk = (const float*)d_in[2];
  const float* Wv = (const float*)d_in[3];
  const float* omg = (const float*)d_in[4];
  float* outp = (float*)d_out;
  char* ws = (char*)d_ws;

  // ws layout (bytes), total 147,423,232 (~141 MB)
  _Float16* wt = (_Float16*)(ws);                 // 6,291,456
  _Float16* om = (_Float16*)(ws + 6291456);       //    32,768
  ushort_t* qkv = (ushort_t*)(ws + 6324224);      // 67,108,864 (Q|K, stride 2048)
  ushort_t* vT = (ushort_t*)(ws + 73433088);      // 33,554,432
  _Float16* xh = (_Float16*)(ws + 106987520);     // 33,554,432
  float* kv = (float*)(ws + 140541952);           // 4,194,304
  float* pksum = (float*)(ws + 144736256);        //    65,536
  ushort_t* kvt = (ushort_t*)(ws + 144801792);    // 2,621,440

  k_wtrans<<<dim3(32, 32, 3), dim3(32, 8), 0, stream>>>(Wq, Wk, Wv, wt);
  k_omconv<<<dim3(64), dim3(256), 0, stream>>>(omg, om);
  k_xconv<<<dim3(8192), dim3(256), 0, stream>>>(x, xh);
  k_gemm<<<dim3(768), dim3(512), 0, stream>>>(xh, wt, qkv, vT);
  hipMemsetAsync(kv, 0, 4194304 + 65536, stream);  // kv + pksum (contiguous)
  k_kv<<<dim3(64, 8), dim3(256), 0, stream>>>(qkv, vT, om, kv, pksum);
  k_kvt<<<dim3(64), dim3(256), 0, stream>>>(kv, pksum, kvt);
  k_out<<<dim3(64, 8), dim3(512), 0, stream>>>(qkv, kvt, om, outp);
}